// Round 1
// baseline (343.056 us; speedup 1.0000x reference)
//
#include <hip/hip_runtime.h>

// MultiheadAttention: B=2, S=4096, D_MODEL=512, NHEAD=4, HEAD_DIM=128
// Pipeline (all bf16 MFMA, fp32 accumulate):
//   proj_kernel x3 : Q/K projections -> [b][h][s][d] bf16 ; V -> [b][h][d][s] (transposed)
//   flash_kernel   : online-softmax attention, S^T orientation (softmax = shuffle reduce)
//   outproj_kernel : attn_out @ Wo^T + bo -> fp32 d_out

#define D_MODEL 512
#define NHEAD 4
#define HD 128
#define S_ 4096

typedef __attribute__((ext_vector_type(8))) short bf16x8;
typedef __attribute__((ext_vector_type(4))) short bf16x4;
typedef __attribute__((ext_vector_type(4))) float f32x4;

__device__ __forceinline__ short f2bf(float f) {
    // round-to-nearest-even fp32 -> bf16 (bit pattern as short)
    unsigned u = __builtin_bit_cast(unsigned, f);
    u += 0x7fffu + ((u >> 16) & 1u);
    return (short)(u >> 16);
}

// ---------------------------------------------------------------------------
// Projection GEMM: out = A(fp32, Mx512) @ W^T(fp32 512x512) + bias
// vmode 0: write bf16 [b][h][s][d]   (Q, K)
// vmode 1: write bf16 [b][h][d][s]   (V transposed, scattered 2B stores; L2 merges)
// 128x128 tile, BK=64, 4 waves each 32 rows x 128 cols.
// LDS tiles XOR-swizzled on 16B granules: phys_granule = kg ^ (row & 7)
// ---------------------------------------------------------------------------
__global__ __launch_bounds__(256) void proj_kernel(
    const float* __restrict__ A, const float* __restrict__ W,
    const float* __restrict__ bias, short* __restrict__ out, int vmode)
{
    __shared__ short lA[128 * 64];
    __shared__ short lB[128 * 64];
    int t = threadIdx.x;
    int wv = t >> 6, ln = t & 63, q4 = ln >> 4, c = ln & 15;
    int m0 = blockIdx.x * 128, n0 = blockIdx.y * 128;
    f32x4 acc[2][8] = {};

    for (int k0 = 0; k0 < 512; k0 += 64) {
        for (int i = 0; i < 4; ++i) {
            int id = i * 256 + t;
            int m = id >> 3, kg = id & 7;
            const float* srcA = A + (size_t)(m0 + m) * 512 + k0 + kg * 8;
            float4 a0 = *(const float4*)srcA;
            float4 a1 = *(const float4*)(srcA + 4);
            bf16x8 va;
            va[0] = f2bf(a0.x); va[1] = f2bf(a0.y); va[2] = f2bf(a0.z); va[3] = f2bf(a0.w);
            va[4] = f2bf(a1.x); va[5] = f2bf(a1.y); va[6] = f2bf(a1.z); va[7] = f2bf(a1.w);
            *(bf16x8*)&lA[m * 64 + ((kg ^ (m & 7)) << 3)] = va;
            const float* srcB = W + (size_t)(n0 + m) * 512 + k0 + kg * 8;
            float4 b0 = *(const float4*)srcB;
            float4 b1 = *(const float4*)(srcB + 4);
            bf16x8 vb;
            vb[0] = f2bf(b0.x); vb[1] = f2bf(b0.y); vb[2] = f2bf(b0.z); vb[3] = f2bf(b0.w);
            vb[4] = f2bf(b1.x); vb[5] = f2bf(b1.y); vb[6] = f2bf(b1.z); vb[7] = f2bf(b1.w);
            *(bf16x8*)&lB[m * 64 + ((kg ^ (m & 7)) << 3)] = vb;
        }
        __syncthreads();
        for (int ks = 0; ks < 2; ++ks) {
            int kg = ks * 4 + q4;
            bf16x8 af[2], bfr[8];
            for (int mt = 0; mt < 2; ++mt) {
                int m = wv * 32 + mt * 16 + c;
                af[mt] = *(bf16x8*)&lA[m * 64 + ((kg ^ (m & 7)) << 3)];
            }
            for (int nt = 0; nt < 8; ++nt) {
                int n = nt * 16 + c;
                bfr[nt] = *(bf16x8*)&lB[n * 64 + ((kg ^ (n & 7)) << 3)];
            }
            for (int mt = 0; mt < 2; ++mt)
                for (int nt = 0; nt < 8; ++nt)
                    acc[mt][nt] = __builtin_amdgcn_mfma_f32_16x16x32_bf16(
                        af[mt], bfr[nt], acc[mt][nt], 0, 0, 0);
        }
        __syncthreads();
    }

    // epilogue: C row = m0+wv*32+mt*16+q4*4+r, col = n0+nt*16+c
    for (int mt = 0; mt < 2; ++mt) {
        for (int nt = 0; nt < 8; ++nt) {
            int col = n0 + nt * 16 + c;
            float bv = bias[col];
            int h = col >> 7, d = col & 127;
            for (int r = 0; r < 4; ++r) {
                int mrow = m0 + wv * 32 + mt * 16 + q4 * 4 + r;
                int b = mrow >> 12, s = mrow & 4095;
                float val = acc[mt][nt][r] + bv;
                size_t idx;
                if (vmode == 0) idx = ((size_t)((b * NHEAD + h) * S_ + s)) * HD + d;
                else            idx = ((size_t)((b * NHEAD + h) * HD + d)) * S_ + s;
                out[idx] = f2bf(val);
            }
        }
    }
}

// ---------------------------------------------------------------------------
// Output projection: out = AO(bf16, Mx512) @ Wo^T + bo -> fp32
// ---------------------------------------------------------------------------
__global__ __launch_bounds__(256) void outproj_kernel(
    const short* __restrict__ A, const float* __restrict__ W,
    const float* __restrict__ bias, float* __restrict__ out)
{
    __shared__ short lA[128 * 64];
    __shared__ short lB[128 * 64];
    int t = threadIdx.x;
    int wv = t >> 6, ln = t & 63, q4 = ln >> 4, c = ln & 15;
    int m0 = blockIdx.x * 128, n0 = blockIdx.y * 128;
    f32x4 acc[2][8] = {};

    for (int k0 = 0; k0 < 512; k0 += 64) {
        for (int i = 0; i < 4; ++i) {
            int id = i * 256 + t;
            int m = id >> 3, kg = id & 7;
            bf16x8 va = *(const bf16x8*)(A + (size_t)(m0 + m) * 512 + k0 + kg * 8);
            *(bf16x8*)&lA[m * 64 + ((kg ^ (m & 7)) << 3)] = va;
            const float* srcB = W + (size_t)(n0 + m) * 512 + k0 + kg * 8;
            float4 b0 = *(const float4*)srcB;
            float4 b1 = *(const float4*)(srcB + 4);
            bf16x8 vb;
            vb[0] = f2bf(b0.x); vb[1] = f2bf(b0.y); vb[2] = f2bf(b0.z); vb[3] = f2bf(b0.w);
            vb[4] = f2bf(b1.x); vb[5] = f2bf(b1.y); vb[6] = f2bf(b1.z); vb[7] = f2bf(b1.w);
            *(bf16x8*)&lB[m * 64 + ((kg ^ (m & 7)) << 3)] = vb;
        }
        __syncthreads();
        for (int ks = 0; ks < 2; ++ks) {
            int kg = ks * 4 + q4;
            bf16x8 af[2], bfr[8];
            for (int mt = 0; mt < 2; ++mt) {
                int m = wv * 32 + mt * 16 + c;
                af[mt] = *(bf16x8*)&lA[m * 64 + ((kg ^ (m & 7)) << 3)];
            }
            for (int nt = 0; nt < 8; ++nt) {
                int n = nt * 16 + c;
                bfr[nt] = *(bf16x8*)&lB[n * 64 + ((kg ^ (n & 7)) << 3)];
            }
            for (int mt = 0; mt < 2; ++mt)
                for (int nt = 0; nt < 8; ++nt)
                    acc[mt][nt] = __builtin_amdgcn_mfma_f32_16x16x32_bf16(
                        af[mt], bfr[nt], acc[mt][nt], 0, 0, 0);
        }
        __syncthreads();
    }

    for (int mt = 0; mt < 2; ++mt) {
        for (int nt = 0; nt < 8; ++nt) {
            int col = n0 + nt * 16 + c;
            float bv = bias[col];
            for (int r = 0; r < 4; ++r) {
                int mrow = m0 + wv * 32 + mt * 16 + q4 * 4 + r;
                out[(size_t)mrow * 512 + col] = acc[mt][nt][r] + bv;
            }
        }
    }
}

// ---------------------------------------------------------------------------
// Flash attention (no mask). One block = one (b,h) x 128-row Q tile.
// 4 waves, each owns 32 q-columns. Computes S^T = K @ Q^T so that:
//   - softmax over keys is a per-lane + shfl_xor(16/32) reduction
//   - P (bf16) goes to LDS as [qq][kk] rows -> PV B-fragments are ds_read_b128
// PV computes O^T[d][qq] = sum_kk VT[d][kk] * P[qq][kk]  (B^T-GEMM form).
// P overlays the K tile region (barrier after QK^T). LDS = exactly 64 KiB.
// ---------------------------------------------------------------------------
__global__ __launch_bounds__(256) void flash_kernel(
    const short* __restrict__ Qh, const short* __restrict__ Kh,
    const short* __restrict__ VTg, short* __restrict__ AO)
{
    __shared__ short lKP[128 * 128];  // K tile, then P tile (per-wave slices)
    __shared__ short lVT[128 * 128];  // V^T tile [d][kk]
    int t = threadIdx.x;
    int wv = t >> 6, ln = t & 63, q4 = ln >> 4, c = ln & 15;
    int s0 = blockIdx.x * 128;
    int bh = blockIdx.y;
    const size_t base = (size_t)bh * S_ * HD;

    // Q fragments held in registers for the whole kernel (loop-invariant)
    bf16x8 qf[2][4];
    for (int qt = 0; qt < 2; ++qt) {
        int s = s0 + wv * 32 + qt * 16 + c;
        const short* qp = Qh + base + (size_t)s * HD + q4 * 8;
        for (int ks = 0; ks < 4; ++ks)
            qf[qt][ks] = *(const bf16x8*)(qp + ks * 32);
    }

    f32x4 of[2][8] = {};                 // O^T accum: [qt][dtile], rows=d, col=qq
    float mrun[2] = {-1e30f, -1e30f};
    float lrun[2] = {0.f, 0.f};
    const float SC = 0.08838834764831845f * 1.4426950408889634f; // 1/sqrt(128)*log2e

    for (int kk0 = 0; kk0 < S_; kk0 += 128) {
        // stage K tile [kk][d] and VT tile [d][kk], XOR-swizzled 16B granules
        for (int i = 0; i < 8; ++i) {
            int id = i * 256 + t;
            int m = id >> 4, kg = id & 15;
            bf16x8 kv = *(const bf16x8*)(Kh + base + (size_t)(kk0 + m) * HD + kg * 8);
            *(bf16x8*)&lKP[m * 128 + ((kg ^ (m & 7)) << 3)] = kv;
            bf16x8 vv = *(const bf16x8*)(VTg + base + (size_t)m * S_ + kk0 + kg * 8);
            *(bf16x8*)&lVT[m * 128 + ((kg ^ (m & 7)) << 3)] = vv;
        }
        __syncthreads();

        // S^T[kk][qq] = K @ Q^T : A = K rows (LDS), B = Q rows (regs)
        f32x4 sf[2][8] = {};
        for (int ks = 0; ks < 4; ++ks) {
            int kg = ks * 4 + q4;
            bf16x8 af[8];
            for (int kt = 0; kt < 8; ++kt) {
                int row = kt * 16 + c;
                af[kt] = *(bf16x8*)&lKP[row * 128 + ((kg ^ (row & 7)) << 3)];
            }
            for (int qt = 0; qt < 2; ++qt)
                for (int kt = 0; kt < 8; ++kt)
                    sf[qt][kt] = __builtin_amdgcn_mfma_f32_16x16x32_bf16(
                        af[kt], qf[qt][ks], sf[qt][kt], 0, 0, 0);
        }
        __syncthreads();  // all waves done reading K before P overwrites lKP

        // online softmax per q-column (col = lane&15 within qt tile)
        for (int qt = 0; qt < 2; ++qt) {
            float mx = -1e30f;
            for (int kt = 0; kt < 8; ++kt)
                for (int r = 0; r < 4; ++r)
                    mx = fmaxf(mx, sf[qt][kt][r]);
            mx = fmaxf(mx, __shfl_xor(mx, 16));
            mx = fmaxf(mx, __shfl_xor(mx, 32));
            float mnew = fmaxf(mrun[qt], mx);
            float alpha = exp2f((mrun[qt] - mnew) * SC);
            mrun[qt] = mnew;
            float lt = 0.f;
            int row = wv * 32 + qt * 16 + c;  // this lane's P row (qq)
            for (int kt = 0; kt < 8; ++kt) {
                bf16x4 pv;
                for (int r = 0; r < 4; ++r) {
                    float p = exp2f((sf[qt][kt][r] - mnew) * SC);
                    lt += p;
                    pv[r] = f2bf(p);
                }
                // logical kk = kt*16 + q4*4 + r -> granule g, half (q4&1)
                int g = kt * 2 + (q4 >> 1);
                int ph = g ^ (row & 7);
                *(bf16x4*)&lKP[row * 128 + (ph << 3) + ((q4 & 1) << 2)] = pv;
            }
            lt += __shfl_xor(lt, 16);
            lt += __shfl_xor(lt, 32);
            lrun[qt] = lrun[qt] * alpha + lt;
            for (int dt = 0; dt < 8; ++dt)
                of[qt][dt] *= alpha;
        }

        // O^T += VT @ P^T : A = VT rows (LDS), B = P rows (own-wave LDS slice)
        for (int ks = 0; ks < 4; ++ks) {
            int kg = ks * 4 + q4;
            bf16x8 av[8], bp[2];
            for (int dt = 0; dt < 8; ++dt) {
                int row = dt * 16 + c;
                av[dt] = *(bf16x8*)&lVT[row * 128 + ((kg ^ (row & 7)) << 3)];
            }
            for (int qt = 0; qt < 2; ++qt) {
                int row = wv * 32 + qt * 16 + c;
                bp[qt] = *(bf16x8*)&lKP[row * 128 + ((kg ^ (row & 7)) << 3)];
            }
            for (int qt = 0; qt < 2; ++qt)
                for (int dt = 0; dt < 8; ++dt)
                    of[qt][dt] = __builtin_amdgcn_mfma_f32_16x16x32_bf16(
                        av[dt], bp[qt], of[qt][dt], 0, 0, 0);
        }
        __syncthreads();  // before restaging K/VT
    }

    // epilogue: O = O^T / l, store bf16 to AO[b][s][h*128+d]
    int b = bh >> 2, h = bh & 3;
    for (int qt = 0; qt < 2; ++qt) {
        float inv = 1.0f / lrun[qt];
        int s = s0 + wv * 32 + qt * 16 + c;
        short* dst = AO + ((size_t)(b * S_ + s)) * D_MODEL + h * HD;
        for (int dt = 0; dt < 8; ++dt) {
            bf16x4 ov;
            for (int r = 0; r < 4; ++r) ov[r] = f2bf(of[qt][dt][r] * inv);
            *(bf16x4*)(dst + dt * 16 + q4 * 4) = ov;
        }
    }
}

// ---------------------------------------------------------------------------
extern "C" void kernel_launch(void* const* d_in, const int* in_sizes, int n_in,
                              void* d_out, int out_size, void* d_ws, size_t ws_size,
                              hipStream_t stream) {
    const float* q  = (const float*)d_in[0];
    const float* k  = (const float*)d_in[1];
    const float* v  = (const float*)d_in[2];
    const float* Wq = (const float*)d_in[3];
    const float* bq = (const float*)d_in[4];
    const float* Wk = (const float*)d_in[5];
    const float* bk = (const float*)d_in[6];
    const float* Wv = (const float*)d_in[7];
    const float* bv = (const float*)d_in[8];
    const float* Wo = (const float*)d_in[9];
    const float* bo = (const float*)d_in[10];

    short* ws = (short*)d_ws;
    const size_t HS = (size_t)2 * NHEAD * S_ * HD;  // 4194304 elems per tensor
    short* Qh = ws;
    short* Kh = ws + HS;
    short* VT = ws + 2 * HS;
    short* AO = ws + 3 * HS;

    dim3 g(64, 4), blk(256);
    proj_kernel<<<g, blk, 0, stream>>>(q, Wq, bq, Qh, 0);
    proj_kernel<<<g, blk, 0, stream>>>(k, Wk, bk, Kh, 0);
    proj_kernel<<<g, blk, 0, stream>>>(v, Wv, bv, VT, 1);
    flash_kernel<<<dim3(32, 8), blk, 0, stream>>>(Qh, Kh, VT, AO);
    outproj_kernel<<<g, blk, 0, stream>>>(AO, Wo, bo, (float*)d_out);
}

// Round 2
// 323.309 us; speedup vs baseline: 1.0611x; 1.0611x over previous
//
#include <hip/hip_runtime.h>

// MultiheadAttention: B=2, S=4096, D_MODEL=512, NHEAD=4, HEAD_DIM=128
// R2: K-split flash decoding (2 blocks/CU), 64x128 proj tiles (512 blocks),
//     LDS-transposed V store, alpha-rescale skip.

#define D_MODEL 512
#define NHEAD 4
#define HD 128
#define S_ 4096

typedef __attribute__((ext_vector_type(8))) short bf16x8;
typedef __attribute__((ext_vector_type(4))) short bf16x4;
typedef __attribute__((ext_vector_type(4))) float f32x4;

__device__ __forceinline__ short f2bf(float f) {
    unsigned u = __builtin_bit_cast(unsigned, f);
    u += 0x7fffu + ((u >> 16) & 1u);
    return (short)(u >> 16);
}

// ---------------------------------------------------------------------------
// Projection GEMM: out = A(fp32, Mx512) @ W^T(fp32 512x512) + bias -> bf16
// 64x128 tile, BK=64, 4 waves each 16 rows x 128 cols. 512 blocks.
// vmode 0: out [b][h][s][d]; vmode 1: out [b][h][d][s] via LDS transpose.
// ---------------------------------------------------------------------------
__global__ __launch_bounds__(256) void proj_kernel(
    const float* __restrict__ A, const float* __restrict__ W,
    const float* __restrict__ bias, short* __restrict__ out, int vmode)
{
    __shared__ short lA[64 * 64];    // 8 KiB
    __shared__ short lB[128 * 64];   // 16 KiB
    int t = threadIdx.x;
    int wv = t >> 6, ln = t & 63, q4 = ln >> 4, c = ln & 15;
    int m0 = blockIdx.x * 64, n0 = blockIdx.y * 128;
    f32x4 acc[8] = {};

    for (int k0 = 0; k0 < 512; k0 += 64) {
        {   // stage A: 64 rows x 8 granules = 512
            for (int i = 0; i < 2; ++i) {
                int id = i * 256 + t;
                int m = id >> 3, kg = id & 7;
                const float* src = A + (size_t)(m0 + m) * 512 + k0 + kg * 8;
                float4 a0 = *(const float4*)src;
                float4 a1 = *(const float4*)(src + 4);
                bf16x8 va;
                va[0] = f2bf(a0.x); va[1] = f2bf(a0.y); va[2] = f2bf(a0.z); va[3] = f2bf(a0.w);
                va[4] = f2bf(a1.x); va[5] = f2bf(a1.y); va[6] = f2bf(a1.z); va[7] = f2bf(a1.w);
                *(bf16x8*)&lA[m * 64 + ((kg ^ (m & 7)) << 3)] = va;
            }
            // stage B: 128 rows x 8 granules = 1024
            for (int i = 0; i < 4; ++i) {
                int id = i * 256 + t;
                int n = id >> 3, kg = id & 7;
                const float* src = W + (size_t)(n0 + n) * 512 + k0 + kg * 8;
                float4 b0 = *(const float4*)src;
                float4 b1 = *(const float4*)(src + 4);
                bf16x8 vb;
                vb[0] = f2bf(b0.x); vb[1] = f2bf(b0.y); vb[2] = f2bf(b0.z); vb[3] = f2bf(b0.w);
                vb[4] = f2bf(b1.x); vb[5] = f2bf(b1.y); vb[6] = f2bf(b1.z); vb[7] = f2bf(b1.w);
                *(bf16x8*)&lB[n * 64 + ((kg ^ (n & 7)) << 3)] = vb;
            }
        }
        __syncthreads();
        for (int ks = 0; ks < 2; ++ks) {
            int kg = ks * 4 + q4;
            int m = wv * 16 + c;
            bf16x8 af = *(bf16x8*)&lA[m * 64 + ((kg ^ (m & 7)) << 3)];
            bf16x8 bfr[8];
            for (int nt = 0; nt < 8; ++nt) {
                int n = nt * 16 + c;
                bfr[nt] = *(bf16x8*)&lB[n * 64 + ((kg ^ (n & 7)) << 3)];
            }
            for (int nt = 0; nt < 8; ++nt)
                acc[nt] = __builtin_amdgcn_mfma_f32_16x16x32_bf16(af, bfr[nt], acc[nt], 0, 0, 0);
        }
        __syncthreads();
    }

    if (vmode == 0) {
        // C row = m0 + wv*16 + q4*4 + r, col = n0 + nt*16 + c
        for (int nt = 0; nt < 8; ++nt) {
            int col = n0 + nt * 16 + c;
            float bv = bias[col];
            int h = col >> 7, d = col & 127;
            for (int r = 0; r < 4; ++r) {
                int mrow = m0 + wv * 16 + q4 * 4 + r;
                int b = mrow >> 12, s = mrow & 4095;
                out[((size_t)((b * NHEAD + h) * S_ + s)) * HD + d] = f2bf(acc[nt][r] + bv);
            }
        }
    } else {
        // transpose tile [d 128][s 64] in lB, then coalesced 8B row stores
        for (int nt = 0; nt < 8; ++nt) {
            int d = nt * 16 + c;                 // local d 0..127
            float bv = bias[n0 + d];
            bf16x4 pv;
            for (int r = 0; r < 4; ++r) pv[r] = f2bf(acc[nt][r] + bv);
            int gr = wv * 4 + q4;                // s-granule 0..15 (4 shorts each)
            *(bf16x4*)&lB[d * 64 + ((gr ^ (d & 15)) << 2)] = pv;
        }
        __syncthreads();
        int b = m0 >> 12, sbase = m0 & 4095, h = blockIdx.y;
        for (int i = 0; i < 8; ++i) {
            int id = i * 256 + t;
            int d = id >> 4, grl = id & 15;
            bf16x4 v = *(bf16x4*)&lB[d * 64 + ((grl ^ (d & 15)) << 2)];
            *(bf16x4*)&out[((size_t)((b * NHEAD + h) * HD + d)) * S_ + sbase + grl * 4] = v;
        }
    }
}

// ---------------------------------------------------------------------------
// Output projection: out = AO(bf16, Mx512) @ Wo^T + bo -> fp32. 64x128 tiles.
// ---------------------------------------------------------------------------
__global__ __launch_bounds__(256) void outproj_kernel(
    const short* __restrict__ A, const float* __restrict__ W,
    const float* __restrict__ bias, float* __restrict__ out)
{
    __shared__ short lA[64 * 64];
    __shared__ short lB[128 * 64];
    int t = threadIdx.x;
    int wv = t >> 6, ln = t & 63, q4 = ln >> 4, c = ln & 15;
    int m0 = blockIdx.x * 64, n0 = blockIdx.y * 128;
    f32x4 acc[8] = {};

    for (int k0 = 0; k0 < 512; k0 += 64) {
        for (int i = 0; i < 2; ++i) {
            int id = i * 256 + t;
            int m = id >> 3, kg = id & 7;
            bf16x8 va = *(const bf16x8*)(A + (size_t)(m0 + m) * 512 + k0 + kg * 8);
            *(bf16x8*)&lA[m * 64 + ((kg ^ (m & 7)) << 3)] = va;
        }
        for (int i = 0; i < 4; ++i) {
            int id = i * 256 + t;
            int n = id >> 3, kg = id & 7;
            const float* src = W + (size_t)(n0 + n) * 512 + k0 + kg * 8;
            float4 b0 = *(const float4*)src;
            float4 b1 = *(const float4*)(src + 4);
            bf16x8 vb;
            vb[0] = f2bf(b0.x); vb[1] = f2bf(b0.y); vb[2] = f2bf(b0.z); vb[3] = f2bf(b0.w);
            vb[4] = f2bf(b1.x); vb[5] = f2bf(b1.y); vb[6] = f2bf(b1.z); vb[7] = f2bf(b1.w);
            *(bf16x8*)&lB[n * 64 + ((kg ^ (n & 7)) << 3)] = vb;
        }
        __syncthreads();
        for (int ks = 0; ks < 2; ++ks) {
            int kg = ks * 4 + q4;
            int m = wv * 16 + c;
            bf16x8 af = *(bf16x8*)&lA[m * 64 + ((kg ^ (m & 7)) << 3)];
            bf16x8 bfr[8];
            for (int nt = 0; nt < 8; ++nt) {
                int n = nt * 16 + c;
                bfr[nt] = *(bf16x8*)&lB[n * 64 + ((kg ^ (n & 7)) << 3)];
            }
            for (int nt = 0; nt < 8; ++nt)
                acc[nt] = __builtin_amdgcn_mfma_f32_16x16x32_bf16(af, bfr[nt], acc[nt], 0, 0, 0);
        }
        __syncthreads();
    }

    for (int nt = 0; nt < 8; ++nt) {
        int col = n0 + nt * 16 + c;
        float bv = bias[col];
        for (int r = 0; r < 4; ++r) {
            int mrow = m0 + wv * 16 + q4 * 4 + r;
            out[(size_t)mrow * 512 + col] = acc[nt][r] + bv;
        }
    }
}

// ---------------------------------------------------------------------------
// Flash attention with K-split (flash-decoding). One block = (b,h) x 128-row
// Q tile x one K-range. 4 waves x 32 q-cols, S^T orientation.
// nsplit==1: normalize + write bf16 AO.  nsplit==2: write fp32 U + (m,l).
// ---------------------------------------------------------------------------
__global__ __launch_bounds__(256) void flash_kernel(
    const short* __restrict__ Qh, const short* __restrict__ Kh,
    const short* __restrict__ VTg, short* __restrict__ AO,
    float* __restrict__ U, float* __restrict__ ML, int nsplit, int kkspan)
{
    __shared__ short lKP[128 * 128];
    __shared__ short lVT[128 * 128];
    int t = threadIdx.x;
    int wv = t >> 6, ln = t & 63, q4 = ln >> 4, c = ln & 15;
    int s0 = blockIdx.x * 128;
    int bh = blockIdx.y;
    int z = blockIdx.z;
    const size_t base = (size_t)bh * S_ * HD;

    bf16x8 qf[2][4];
    for (int qt = 0; qt < 2; ++qt) {
        int s = s0 + wv * 32 + qt * 16 + c;
        const short* qp = Qh + base + (size_t)s * HD + q4 * 8;
        for (int ks = 0; ks < 4; ++ks)
            qf[qt][ks] = *(const bf16x8*)(qp + ks * 32);
    }

    f32x4 of[2][8] = {};
    float mrun[2] = {-1e30f, -1e30f};
    float lrun[2] = {0.f, 0.f};
    const float SC = 0.08838834764831845f * 1.4426950408889634f;

    int kkbeg = z * kkspan, kkend = kkbeg + kkspan;
    for (int kk0 = kkbeg; kk0 < kkend; kk0 += 128) {
        for (int i = 0; i < 8; ++i) {
            int id = i * 256 + t;
            int m = id >> 4, kg = id & 15;
            bf16x8 kv = *(const bf16x8*)(Kh + base + (size_t)(kk0 + m) * HD + kg * 8);
            *(bf16x8*)&lKP[m * 128 + ((kg ^ (m & 7)) << 3)] = kv;
            bf16x8 vv = *(const bf16x8*)(VTg + base + (size_t)m * S_ + kk0 + kg * 8);
            *(bf16x8*)&lVT[m * 128 + ((kg ^ (m & 7)) << 3)] = vv;
        }
        __syncthreads();

        f32x4 sf[2][8] = {};
        for (int ks = 0; ks < 4; ++ks) {
            int kg = ks * 4 + q4;
            bf16x8 af[8];
            for (int kt = 0; kt < 8; ++kt) {
                int row = kt * 16 + c;
                af[kt] = *(bf16x8*)&lKP[row * 128 + ((kg ^ (row & 7)) << 3)];
            }
            for (int qt = 0; qt < 2; ++qt)
                for (int kt = 0; kt < 8; ++kt)
                    sf[qt][kt] = __builtin_amdgcn_mfma_f32_16x16x32_bf16(
                        af[kt], qf[qt][ks], sf[qt][kt], 0, 0, 0);
        }
        __syncthreads();

        for (int qt = 0; qt < 2; ++qt) {
            float mx = -1e30f;
            for (int kt = 0; kt < 8; ++kt)
                for (int r = 0; r < 4; ++r)
                    mx = fmaxf(mx, sf[qt][kt][r]);
            mx = fmaxf(mx, __shfl_xor(mx, 16));
            mx = fmaxf(mx, __shfl_xor(mx, 32));
            if (__any(mx > mrun[qt])) {
                float mnew = fmaxf(mrun[qt], mx);
                float alpha = exp2f((mrun[qt] - mnew) * SC);
                mrun[qt] = mnew;
                lrun[qt] *= alpha;
                for (int dt = 0; dt < 8; ++dt)
                    of[qt][dt] *= alpha;
            }
            float mnew = mrun[qt];
            float lt = 0.f;
            int row = wv * 32 + qt * 16 + c;
            for (int kt = 0; kt < 8; ++kt) {
                bf16x4 pv;
                for (int r = 0; r < 4; ++r) {
                    float p = exp2f((sf[qt][kt][r] - mnew) * SC);
                    lt += p;
                    pv[r] = f2bf(p);
                }
                int g = kt * 2 + (q4 >> 1);
                int ph = g ^ (row & 7);
                *(bf16x4*)&lKP[row * 128 + (ph << 3) + ((q4 & 1) << 2)] = pv;
            }
            lt += __shfl_xor(lt, 16);
            lt += __shfl_xor(lt, 32);
            lrun[qt] += lt;
        }

        for (int ks = 0; ks < 4; ++ks) {
            int kg = ks * 4 + q4;
            bf16x8 av[8], bp[2];
            for (int dt = 0; dt < 8; ++dt) {
                int row = dt * 16 + c;
                av[dt] = *(bf16x8*)&lVT[row * 128 + ((kg ^ (row & 7)) << 3)];
            }
            for (int qt = 0; qt < 2; ++qt) {
                int row = wv * 32 + qt * 16 + c;
                bp[qt] = *(bf16x8*)&lKP[row * 128 + ((kg ^ (row & 7)) << 3)];
            }
            for (int qt = 0; qt < 2; ++qt)
                for (int dt = 0; dt < 8; ++dt)
                    of[qt][dt] = __builtin_amdgcn_mfma_f32_16x16x32_bf16(
                        av[dt], bp[qt], of[qt][dt], 0, 0, 0);
        }
        __syncthreads();
    }

    if (nsplit == 2) {
        for (int qt = 0; qt < 2; ++qt) {
            int s = s0 + wv * 32 + qt * 16 + c;
            size_t rowu = (size_t)(z * 8 + bh) * S_ + s;
            float* up = U + rowu * HD;
            for (int dt = 0; dt < 8; ++dt)
                *(f32x4*)&up[dt * 16 + q4 * 4] = of[qt][dt];
            if (q4 == 0) { ML[rowu * 2] = mrun[qt]; ML[rowu * 2 + 1] = lrun[qt]; }
        }
    } else {
        int b = bh >> 2, h = bh & 3;
        for (int qt = 0; qt < 2; ++qt) {
            float inv = 1.0f / lrun[qt];
            int s = s0 + wv * 32 + qt * 16 + c;
            short* dst = AO + ((size_t)(b * S_ + s)) * D_MODEL + h * HD;
            for (int dt = 0; dt < 8; ++dt) {
                bf16x4 ov;
                for (int r = 0; r < 4; ++r) ov[r] = f2bf(of[qt][dt][r] * inv);
                *(bf16x4*)(dst + dt * 16 + q4 * 4) = ov;
            }
        }
    }
}

// ---------------------------------------------------------------------------
// Combine the 2 K-split partials: O = (U0*a0 + U1*a1) / (l0*a0 + l1*a1)
// ---------------------------------------------------------------------------
__global__ __launch_bounds__(256) void combine_kernel(
    const float* __restrict__ U, const float* __restrict__ ML,
    short* __restrict__ AO)
{
    const float SC = 0.08838834764831845f * 1.4426950408889634f;
    int row = blockIdx.x * 8 + (threadIdx.x >> 5);      // (bh,s) row 0..32767
    int d4 = (threadIdx.x & 31) * 4;
    const int R = 8 * S_;
    float m0 = ML[(size_t)row * 2], l0 = ML[(size_t)row * 2 + 1];
    float m1 = ML[((size_t)R + row) * 2], l1 = ML[((size_t)R + row) * 2 + 1];
    float m = fmaxf(m0, m1);
    float a0 = exp2f((m0 - m) * SC), a1 = exp2f((m1 - m) * SC);
    float inv = 1.0f / (l0 * a0 + l1 * a1);
    f32x4 u0 = *(const f32x4*)&U[(size_t)row * HD + d4];
    f32x4 u1 = *(const f32x4*)&U[((size_t)R + row) * HD + d4];
    bf16x4 o;
    for (int j = 0; j < 4; ++j)
        o[j] = f2bf((u0[j] * a0 + u1[j] * a1) * inv);
    int bh = row >> 12, s = row & 4095;
    int b = bh >> 2, h = bh & 3;
    *(bf16x4*)&AO[((size_t)(b * S_ + s)) * D_MODEL + h * HD + d4] = o;
}

// ---------------------------------------------------------------------------
extern "C" void kernel_launch(void* const* d_in, const int* in_sizes, int n_in,
                              void* d_out, int out_size, void* d_ws, size_t ws_size,
                              hipStream_t stream) {
    const float* q  = (const float*)d_in[0];
    const float* k  = (const float*)d_in[1];
    const float* v  = (const float*)d_in[2];
    const float* Wq = (const float*)d_in[3];
    const float* bq = (const float*)d_in[4];
    const float* Wk = (const float*)d_in[5];
    const float* bk = (const float*)d_in[6];
    const float* Wv = (const float*)d_in[7];
    const float* bv = (const float*)d_in[8];
    const float* Wo = (const float*)d_in[9];
    const float* bo = (const float*)d_in[10];

    const size_t HS = (size_t)2 * NHEAD * S_ * HD;      // 4,194,304 elems
    short* ws = (short*)d_ws;
    short* Qh = ws;
    short* Kh = ws + HS;
    short* VT = ws + 2 * HS;
    short* AO = ws + 3 * HS;
    float* U  = (float*)((char*)d_ws + 4 * HS * sizeof(short));   // 32 MB in
    float* ML = U + 2 * HS;                                        // +32 MB

    const size_t NEED = 4 * HS * 2 + 2 * HS * 4 + (size_t)2 * 8 * S_ * 2 * 4;
    int nsplit = (ws_size >= NEED) ? 2 : 1;
    int kkspan = S_ / nsplit;

    dim3 gp(128, 4), blk(256);
    proj_kernel<<<gp, blk, 0, stream>>>(q, Wq, bq, Qh, 0);
    proj_kernel<<<gp, blk, 0, stream>>>(k, Wk, bk, Kh, 0);
    proj_kernel<<<gp, blk, 0, stream>>>(v, Wv, bv, VT, 1);
    flash_kernel<<<dim3(32, 8, nsplit), blk, 0, stream>>>(Qh, Kh, VT, AO, U, ML, nsplit, kkspan);
    if (nsplit == 2)
        combine_kernel<<<dim3(S_), blk, 0, stream>>>(U, ML, AO);
    outproj_kernel<<<gp, blk, 0, stream>>>(AO, Wo, bo, (float*)d_out);
}

// Round 3
// 265.681 us; speedup vs baseline: 1.2912x; 1.2169x over previous
//
#include <hip/hip_runtime.h>

// MultiheadAttention: B=2, S=4096, D_MODEL=512, NHEAD=4, HEAD_DIM=128
// R3: flash with 64-key tiles, wave-private P buffer (48KB LDS, 2 barriers/iter),
//     __launch_bounds__(256,2) to force 2 blocks/CU; fused QKV projection launch.

#define D_MODEL 512
#define NHEAD 4
#define HD 128
#define S_ 4096

typedef __attribute__((ext_vector_type(8))) short bf16x8;
typedef __attribute__((ext_vector_type(4))) short bf16x4;
typedef __attribute__((ext_vector_type(4))) float f32x4;

__device__ __forceinline__ short f2bf(float f) {
    unsigned u = __builtin_bit_cast(unsigned, f);
    u += 0x7fffu + ((u >> 16) & 1u);
    return (short)(u >> 16);
}

// ---------------------------------------------------------------------------
// Fused QKV projection: z=0 -> Q[b][h][s][d], z=1 -> K[b][h][s][d],
// z=2 -> V^T[b][h][d][s] (LDS-transposed store).
// out = A(fp32, Mx512) @ W^T(fp32 512x512) + bias -> bf16. 64x128 tiles.
// ---------------------------------------------------------------------------
__global__ __launch_bounds__(256) void qkv_kernel(
    const float* __restrict__ qin, const float* __restrict__ kin,
    const float* __restrict__ vin,
    const float* __restrict__ Wq, const float* __restrict__ bq,
    const float* __restrict__ Wk, const float* __restrict__ bk,
    const float* __restrict__ Wv, const float* __restrict__ bv,
    short* __restrict__ Qh, short* __restrict__ Kh, short* __restrict__ VT)
{
    __shared__ short lA[64 * 64];
    __shared__ short lB[128 * 64];
    int z = blockIdx.z;
    const float* A    = (z == 0) ? qin : (z == 1) ? kin : vin;
    const float* W    = (z == 0) ? Wq  : (z == 1) ? Wk  : Wv;
    const float* bias = (z == 0) ? bq  : (z == 1) ? bk  : bv;
    short* out        = (z == 0) ? Qh  : (z == 1) ? Kh  : VT;
    int vmode = (z == 2);

    int t = threadIdx.x;
    int wv = t >> 6, ln = t & 63, q4 = ln >> 4, c = ln & 15;
    int m0 = blockIdx.x * 64, n0 = blockIdx.y * 128;
    f32x4 acc[8] = {};

    for (int k0 = 0; k0 < 512; k0 += 64) {
        for (int i = 0; i < 2; ++i) {
            int id = i * 256 + t;
            int m = id >> 3, kg = id & 7;
            const float* src = A + (size_t)(m0 + m) * 512 + k0 + kg * 8;
            float4 a0 = *(const float4*)src;
            float4 a1 = *(const float4*)(src + 4);
            bf16x8 va;
            va[0] = f2bf(a0.x); va[1] = f2bf(a0.y); va[2] = f2bf(a0.z); va[3] = f2bf(a0.w);
            va[4] = f2bf(a1.x); va[5] = f2bf(a1.y); va[6] = f2bf(a1.z); va[7] = f2bf(a1.w);
            *(bf16x8*)&lA[m * 64 + ((kg ^ (m & 7)) << 3)] = va;
        }
        for (int i = 0; i < 4; ++i) {
            int id = i * 256 + t;
            int n = id >> 3, kg = id & 7;
            const float* src = W + (size_t)(n0 + n) * 512 + k0 + kg * 8;
            float4 b0 = *(const float4*)src;
            float4 b1 = *(const float4*)(src + 4);
            bf16x8 vb;
            vb[0] = f2bf(b0.x); vb[1] = f2bf(b0.y); vb[2] = f2bf(b0.z); vb[3] = f2bf(b0.w);
            vb[4] = f2bf(b1.x); vb[5] = f2bf(b1.y); vb[6] = f2bf(b1.z); vb[7] = f2bf(b1.w);
            *(bf16x8*)&lB[n * 64 + ((kg ^ (n & 7)) << 3)] = vb;
        }
        __syncthreads();
        for (int ks = 0; ks < 2; ++ks) {
            int kg = ks * 4 + q4;
            int m = wv * 16 + c;
            bf16x8 af = *(bf16x8*)&lA[m * 64 + ((kg ^ (m & 7)) << 3)];
            bf16x8 bfr[8];
            for (int nt = 0; nt < 8; ++nt) {
                int n = nt * 16 + c;
                bfr[nt] = *(bf16x8*)&lB[n * 64 + ((kg ^ (n & 7)) << 3)];
            }
            for (int nt = 0; nt < 8; ++nt)
                acc[nt] = __builtin_amdgcn_mfma_f32_16x16x32_bf16(af, bfr[nt], acc[nt], 0, 0, 0);
        }
        __syncthreads();
    }

    if (vmode == 0) {
        for (int nt = 0; nt < 8; ++nt) {
            int col = n0 + nt * 16 + c;
            float bv = bias[col];
            int h = col >> 7, d = col & 127;
            for (int r = 0; r < 4; ++r) {
                int mrow = m0 + wv * 16 + q4 * 4 + r;
                int b = mrow >> 12, s = mrow & 4095;
                out[((size_t)((b * NHEAD + h) * S_ + s)) * HD + d] = f2bf(acc[nt][r] + bv);
            }
        }
    } else {
        for (int nt = 0; nt < 8; ++nt) {
            int d = nt * 16 + c;
            float bv = bias[n0 + d];
            bf16x4 pv;
            for (int r = 0; r < 4; ++r) pv[r] = f2bf(acc[nt][r] + bv);
            int gr = wv * 4 + q4;
            *(bf16x4*)&lB[d * 64 + ((gr ^ (d & 15)) << 2)] = pv;
        }
        __syncthreads();
        int b = m0 >> 12, sbase = m0 & 4095, h = blockIdx.y;
        for (int i = 0; i < 8; ++i) {
            int id = i * 256 + t;
            int d = id >> 4, grl = id & 15;
            bf16x4 v = *(bf16x4*)&lB[d * 64 + ((grl ^ (d & 15)) << 2)];
            *(bf16x4*)&out[((size_t)((b * NHEAD + h) * HD + d)) * S_ + sbase + grl * 4] = v;
        }
    }
}

// ---------------------------------------------------------------------------
// Output projection: out = AO(bf16, Mx512) @ Wo^T + bo -> fp32. 64x128 tiles.
// ---------------------------------------------------------------------------
__global__ __launch_bounds__(256) void outproj_kernel(
    const short* __restrict__ A, const float* __restrict__ W,
    const float* __restrict__ bias, float* __restrict__ out)
{
    __shared__ short lA[64 * 64];
    __shared__ short lB[128 * 64];
    int t = threadIdx.x;
    int wv = t >> 6, ln = t & 63, q4 = ln >> 4, c = ln & 15;
    int m0 = blockIdx.x * 64, n0 = blockIdx.y * 128;
    f32x4 acc[8] = {};

    for (int k0 = 0; k0 < 512; k0 += 64) {
        for (int i = 0; i < 2; ++i) {
            int id = i * 256 + t;
            int m = id >> 3, kg = id & 7;
            bf16x8 va = *(const bf16x8*)(A + (size_t)(m0 + m) * 512 + k0 + kg * 8);
            *(bf16x8*)&lA[m * 64 + ((kg ^ (m & 7)) << 3)] = va;
        }
        for (int i = 0; i < 4; ++i) {
            int id = i * 256 + t;
            int n = id >> 3, kg = id & 7;
            const float* src = W + (size_t)(n0 + n) * 512 + k0 + kg * 8;
            float4 b0 = *(const float4*)src;
            float4 b1 = *(const float4*)(src + 4);
            bf16x8 vb;
            vb[0] = f2bf(b0.x); vb[1] = f2bf(b0.y); vb[2] = f2bf(b0.z); vb[3] = f2bf(b0.w);
            vb[4] = f2bf(b1.x); vb[5] = f2bf(b1.y); vb[6] = f2bf(b1.z); vb[7] = f2bf(b1.w);
            *(bf16x8*)&lB[n * 64 + ((kg ^ (n & 7)) << 3)] = vb;
        }
        __syncthreads();
        for (int ks = 0; ks < 2; ++ks) {
            int kg = ks * 4 + q4;
            int m = wv * 16 + c;
            bf16x8 af = *(bf16x8*)&lA[m * 64 + ((kg ^ (m & 7)) << 3)];
            bf16x8 bfr[8];
            for (int nt = 0; nt < 8; ++nt) {
                int n = nt * 16 + c;
                bfr[nt] = *(bf16x8*)&lB[n * 64 + ((kg ^ (n & 7)) << 3)];
            }
            for (int nt = 0; nt < 8; ++nt)
                acc[nt] = __builtin_amdgcn_mfma_f32_16x16x32_bf16(af, bfr[nt], acc[nt], 0, 0, 0);
        }
        __syncthreads();
    }

    for (int nt = 0; nt < 8; ++nt) {
        int col = n0 + nt * 16 + c;
        float bv = bias[col];
        for (int r = 0; r < 4; ++r) {
            int mrow = m0 + wv * 16 + q4 * 4 + r;
            out[(size_t)mrow * 512 + col] = acc[nt][r] + bv;
        }
    }
}

// ---------------------------------------------------------------------------
// Flash attention, 64-key tiles, wave-private P buffer, K-split.
// Block = (q-tile 128) x (b,h) x (K-range). 4 waves x 32 q, S^T orientation.
// LDS 48KB; __launch_bounds__(256,2) forces <=256 VGPR+AGPR -> 2 blocks/CU.
// ---------------------------------------------------------------------------
__global__ __launch_bounds__(256, 2) void flash_kernel(
    const short* __restrict__ Qh, const short* __restrict__ Kh,
    const short* __restrict__ VTg, short* __restrict__ AO,
    float* __restrict__ U, float* __restrict__ ML, int nsplit, int kkspan)
{
    __shared__ short lK[64 * 128];    // 16 KB: K tile [key][hd]
    __shared__ short lVT[128 * 64];   // 16 KB: V^T tile [d][key]
    __shared__ short lP[4 * 32 * 64]; // 16 KB: per-wave P [q][key]
    int t = threadIdx.x;
    int wv = t >> 6, ln = t & 63, q4 = ln >> 4, c = ln & 15;
    int s0 = blockIdx.x * 128;
    int bh = blockIdx.y;
    int z = blockIdx.z;
    const size_t base = (size_t)bh * S_ * HD;
    short* myP = &lP[wv * 2048];

    bf16x8 qf[2][4];
    for (int qt = 0; qt < 2; ++qt) {
        int s = s0 + wv * 32 + qt * 16 + c;
        const short* qp = Qh + base + (size_t)s * HD + q4 * 8;
        for (int ks = 0; ks < 4; ++ks)
            qf[qt][ks] = *(const bf16x8*)(qp + ks * 32);
    }

    f32x4 of[2][8] = {};
    float mrun[2] = {-1e30f, -1e30f};
    float lrun[2] = {0.f, 0.f};
    const float SC = 0.08838834764831845f * 1.4426950408889634f;

    int kkbeg = z * kkspan, kkend = kkbeg + kkspan;
    for (int kk0 = kkbeg; kk0 < kkend; kk0 += 64) {
        // stage K (64x128) and VT (128x64)
        for (int i = 0; i < 4; ++i) {
            int id = i * 256 + t;
            int m = id >> 4, kg = id & 15;
            bf16x8 kv = *(const bf16x8*)(Kh + base + (size_t)(kk0 + m) * HD + kg * 8);
            *(bf16x8*)&lK[m * 128 + ((kg ^ (m & 7)) << 3)] = kv;
            int mv = id >> 3, kgv = id & 7;
            bf16x8 vv = *(const bf16x8*)(VTg + base + (size_t)mv * S_ + kk0 + kgv * 8);
            *(bf16x8*)&lVT[mv * 64 + ((kgv ^ (mv & 7)) << 3)] = vv;
        }
        __syncthreads();

        // S^T[key][q] = K @ Q^T
        f32x4 sf[2][4] = {};
        for (int ks = 0; ks < 4; ++ks) {
            int kg = ks * 4 + q4;
            bf16x8 af[4];
            for (int kt = 0; kt < 4; ++kt) {
                int row = kt * 16 + c;
                af[kt] = *(bf16x8*)&lK[row * 128 + ((kg ^ (row & 7)) << 3)];
            }
            for (int qt = 0; qt < 2; ++qt)
                for (int kt = 0; kt < 4; ++kt)
                    sf[qt][kt] = __builtin_amdgcn_mfma_f32_16x16x32_bf16(
                        af[kt], qf[qt][ks], sf[qt][kt], 0, 0, 0);
        }

        // online softmax (keys spread over kt,q4,r; q = c within qt tile)
        for (int qt = 0; qt < 2; ++qt) {
            float mx = -1e30f;
            for (int kt = 0; kt < 4; ++kt)
                for (int r = 0; r < 4; ++r)
                    mx = fmaxf(mx, sf[qt][kt][r]);
            mx = fmaxf(mx, __shfl_xor(mx, 16));
            mx = fmaxf(mx, __shfl_xor(mx, 32));
            if (__any(mx > mrun[qt])) {
                float mnew = fmaxf(mrun[qt], mx);
                float alpha = exp2f((mrun[qt] - mnew) * SC);
                mrun[qt] = mnew;
                lrun[qt] *= alpha;
                for (int dt = 0; dt < 8; ++dt)
                    of[qt][dt] *= alpha;
            }
            float mnew = mrun[qt];
            float lt = 0.f;
            int rq = qt * 16 + c;                 // P row (this wave's slice)
            for (int kt = 0; kt < 4; ++kt) {
                bf16x4 pv;
                for (int r = 0; r < 4; ++r) {
                    float p = exp2f((sf[qt][kt][r] - mnew) * SC);
                    lt += p;
                    pv[r] = f2bf(p);
                }
                int g = kt * 2 + (q4 >> 1);       // key granule
                *(bf16x4*)&myP[rq * 64 + ((g ^ (c & 7)) << 3) + ((q4 & 1) << 2)] = pv;
            }
            lt += __shfl_xor(lt, 16);
            lt += __shfl_xor(lt, 32);
            lrun[qt] += lt;
        }

        // O^T += VT @ P^T   (P is wave-private: no barrier needed)
        for (int ksv = 0; ksv < 2; ++ksv) {
            int kg = ksv * 4 + q4;
            bf16x8 av[8], bp[2];
            for (int dt = 0; dt < 8; ++dt) {
                int row = dt * 16 + c;
                av[dt] = *(bf16x8*)&lVT[row * 64 + ((kg ^ (row & 7)) << 3)];
            }
            for (int qt = 0; qt < 2; ++qt) {
                int rq = qt * 16 + c;
                bp[qt] = *(bf16x8*)&myP[rq * 64 + ((kg ^ (c & 7)) << 3)];
            }
            for (int qt = 0; qt < 2; ++qt)
                for (int dt = 0; dt < 8; ++dt)
                    of[qt][dt] = __builtin_amdgcn_mfma_f32_16x16x32_bf16(
                        av[dt], bp[qt], of[qt][dt], 0, 0, 0);
        }
        __syncthreads();   // before next stage overwrites lK/lVT
    }

    if (nsplit == 2) {
        for (int qt = 0; qt < 2; ++qt) {
            int s = s0 + wv * 32 + qt * 16 + c;
            size_t rowu = (size_t)(z * 8 + bh) * S_ + s;
            float* up = U + rowu * HD;
            for (int dt = 0; dt < 8; ++dt)
                *(f32x4*)&up[dt * 16 + q4 * 4] = of[qt][dt];
            if (q4 == 0) { ML[rowu * 2] = mrun[qt]; ML[rowu * 2 + 1] = lrun[qt]; }
        }
    } else {
        int b = bh >> 2, h = bh & 3;
        for (int qt = 0; qt < 2; ++qt) {
            float inv = 1.0f / lrun[qt];
            int s = s0 + wv * 32 + qt * 16 + c;
            short* dst = AO + ((size_t)(b * S_ + s)) * D_MODEL + h * HD;
            for (int dt = 0; dt < 8; ++dt) {
                bf16x4 ov;
                for (int r = 0; r < 4; ++r) ov[r] = f2bf(of[qt][dt][r] * inv);
                *(bf16x4*)(dst + dt * 16 + q4 * 4) = ov;
            }
        }
    }
}

// ---------------------------------------------------------------------------
// Combine the 2 K-split partials: O = (U0*a0 + U1*a1) / (l0*a0 + l1*a1)
// ---------------------------------------------------------------------------
__global__ __launch_bounds__(256) void combine_kernel(
    const float* __restrict__ U, const float* __restrict__ ML,
    short* __restrict__ AO)
{
    const float SC = 0.08838834764831845f * 1.4426950408889634f;
    int row = blockIdx.x * 8 + (threadIdx.x >> 5);
    int d4 = (threadIdx.x & 31) * 4;
    const int R = 8 * S_;
    float m0 = ML[(size_t)row * 2], l0 = ML[(size_t)row * 2 + 1];
    float m1 = ML[((size_t)R + row) * 2], l1 = ML[((size_t)R + row) * 2 + 1];
    float m = fmaxf(m0, m1);
    float a0 = exp2f((m0 - m) * SC), a1 = exp2f((m1 - m) * SC);
    float inv = 1.0f / (l0 * a0 + l1 * a1);
    f32x4 u0 = *(const f32x4*)&U[(size_t)row * HD + d4];
    f32x4 u1 = *(const f32x4*)&U[((size_t)R + row) * HD + d4];
    bf16x4 o;
    for (int j = 0; j < 4; ++j)
        o[j] = f2bf((u0[j] * a0 + u1[j] * a1) * inv);
    int bh = row >> 12, s = row & 4095;
    int b = bh >> 2, h = bh & 3;
    *(bf16x4*)&AO[((size_t)(b * S_ + s)) * D_MODEL + h * HD + d4] = o;
}

// ---------------------------------------------------------------------------
extern "C" void kernel_launch(void* const* d_in, const int* in_sizes, int n_in,
                              void* d_out, int out_size, void* d_ws, size_t ws_size,
                              hipStream_t stream) {
    const float* q  = (const float*)d_in[0];
    const float* k  = (const float*)d_in[1];
    const float* v  = (const float*)d_in[2];
    const float* Wq = (const float*)d_in[3];
    const float* bq = (const float*)d_in[4];
    const float* Wk = (const float*)d_in[5];
    const float* bk = (const float*)d_in[6];
    const float* Wv = (const float*)d_in[7];
    const float* bv = (const float*)d_in[8];
    const float* Wo = (const float*)d_in[9];
    const float* bo = (const float*)d_in[10];

    const size_t HS = (size_t)2 * NHEAD * S_ * HD;      // 4,194,304 elems
    short* ws = (short*)d_ws;
    short* Qh = ws;
    short* Kh = ws + HS;
    short* VT = ws + 2 * HS;
    short* AO = ws + 3 * HS;
    float* U  = (float*)((char*)d_ws + 4 * HS * sizeof(short));
    float* ML = U + 2 * HS;

    const size_t NEED = 4 * HS * 2 + 2 * HS * 4 + (size_t)2 * 8 * S_ * 2 * 4;
    int nsplit = (ws_size >= NEED) ? 2 : 1;
    int kkspan = S_ / nsplit;

    dim3 blk(256);
    qkv_kernel<<<dim3(128, 4, 3), blk, 0, stream>>>(q, k, v, Wq, bq, Wk, bk, Wv, bv, Qh, Kh, VT);
    flash_kernel<<<dim3(32, 8, nsplit), blk, 0, stream>>>(Qh, Kh, VT, AO, U, ML, nsplit, kkspan);
    if (nsplit == 2)
        combine_kernel<<<dim3(S_), blk, 0, stream>>>(U, ML, AO);
    outproj_kernel<<<dim3(128, 4), blk, 0, stream>>>(AO, Wo, bo, (float*)d_out);
}